// Round 4
// baseline (219.008 us; speedup 1.0000x reference)
//
#include <hip/hip_runtime.h>

typedef __attribute__((ext_vector_type(8))) short short8_t;
typedef __attribute__((ext_vector_type(4))) short short4_t;
typedef __attribute__((ext_vector_type(4))) float float4_t;
typedef __attribute__((ext_vector_type(2))) unsigned int uint2_t;

__device__ __forceinline__ unsigned short f2bf(float f) {
    unsigned u = __builtin_bit_cast(unsigned, f);
    u += 0x7FFFu + ((u >> 16) & 1u);
    return (unsigned short)(u >> 16);
}

// two f32 -> packed 2x bf16 (RNE) in one instruction
__device__ __forceinline__ unsigned pk_bf16(float a, float b) {
    unsigned r;
    asm("v_cvt_pk_bf16_f32 %0, %1, %2" : "=v"(r) : "v"(a), "v"(b));
    return r;
}

#define MFMA(A, B, C) __builtin_amdgcn_mfma_f32_16x16x32_bf16((A), (B), (C), 0, 0, 0)

// ---------------------------------------------------------------------------
// Kernel 1: per-head Lorentz FC projections (round-2 measured structure).
// grid = (64 row-tiles of 64, 8 heads, 3 mats). block = 256. 3 blocks/CU.
// mat 0 -> Qsgn [H][4096][128] bf16, comp0 = -t_q (Minkowski sign folded in)
// mat 1 -> K    [H][4096][128] bf16, comp0 = +t_k
// mat 2 -> Vt   [H][B=4][128][1024] bf16 (transposed: d-major), row 0 is t_v
// ---------------------------------------------------------------------------
__global__ __launch_bounds__(256) void k_proj(
    const float* __restrict__ x,
    const float* __restrict__ Wq, const float* __restrict__ bq,
    const float* __restrict__ Wk, const float* __restrict__ bk,
    const float* __restrict__ Wv, const float* __restrict__ bv,
    unsigned short* __restrict__ Qs, unsigned short* __restrict__ Kb,
    unsigned short* __restrict__ Vt)
{
    __shared__ __align__(16) unsigned char lds[17408 + 34816 + 1024];
    unsigned short* Xs  = (unsigned short*)lds;                    // [64][136] bf16
    unsigned short* Ws  = (unsigned short*)(lds + 17408);          // [128][136] bf16
    float*          ssqB = (float*)(lds + 17408 + 34816);          // [64][4]
    unsigned short* Ot  = Ws;                                      // reuse after MFMA
    unsigned short* OtT = Ws;                                      // mat=2: [128][72]

    const int tid = threadIdx.x;
    const int m0  = blockIdx.x * 64;
    const int h   = blockIdx.y;
    const int mat = blockIdx.z;
    const float* W  = (mat == 0) ? Wq : ((mat == 1) ? Wk : Wv);
    const float* bb = (mat == 0) ? bq : ((mat == 1) ? bk : bv);

    // stage X tile (64 x 128, fp32 -> bf16)
    #pragma unroll
    for (int p = 0; p < 8; p++) {
        int r = p * 8 + (tid >> 5), c = (tid & 31) * 4;
        float4_t v = *(const float4_t*)(x + (m0 + r) * 128 + c);
        uint2_t u; u[0] = pk_bf16(v[0], v[1]); u[1] = pk_bf16(v[2], v[3]);
        *(uint2_t*)(Xs + r * 136 + c) = u;
    }
    // stage W (127 x 128, zero row 127)
    #pragma unroll
    for (int p = 0; p < 16; p++) {
        int e = p * 8 + (tid >> 5), c = (tid & 31) * 4;
        float4_t v = {0.f, 0.f, 0.f, 0.f};
        if (e < 127) v = *(const float4_t*)(W + (h * 127 + e) * 128 + c);
        uint2_t u; u[0] = pk_bf16(v[0], v[1]); u[1] = pk_bf16(v[2], v[3]);
        *(uint2_t*)(Ws + e * 136 + c) = u;
    }
    __syncthreads();

    const int w = tid >> 6, lane = tid & 63, li = lane & 15, lg = lane >> 4;
    float4_t acc[4][2];
    #pragma unroll
    for (int i = 0; i < 4; i++)
        #pragma unroll
        for (int j = 0; j < 2; j++) acc[i][j] = (float4_t){0.f, 0.f, 0.f, 0.f};

    #pragma unroll
    for (int kk = 0; kk < 4; kk++) {
        short8_t Bf[2];
        #pragma unroll
        for (int ni = 0; ni < 2; ni++)
            Bf[ni] = *(short8_t*)(Ws + (w * 32 + ni * 16 + li) * 136 + kk * 32 + lg * 8);
        #pragma unroll
        for (int mi = 0; mi < 4; mi++) {
            short8_t A = *(short8_t*)(Xs + (mi * 16 + li) * 136 + kk * 32 + lg * 8);
            #pragma unroll
            for (int ni = 0; ni < 2; ni++) acc[mi][ni] = MFMA(A, Bf[ni], acc[mi][ni]);
        }
    }
    // bias
    #pragma unroll
    for (int ni = 0; ni < 2; ni++) {
        int e = w * 32 + ni * 16 + li;
        float bvv = (e < 127) ? bb[h * 127 + e] : 0.0f;
        #pragma unroll
        for (int mi = 0; mi < 4; mi++)
            #pragma unroll
            for (int r = 0; r < 4; r++) acc[mi][ni][r] += bvv;
    }
    // per-row sum of squares of space components (this wave's 32 cols)
    #pragma unroll
    for (int mi = 0; mi < 4; mi++) {
        #pragma unroll
        for (int r = 0; r < 4; r++) {
            float s = acc[mi][0][r] * acc[mi][0][r] + acc[mi][1][r] * acc[mi][1][r];
            s += __shfl_xor(s, 1);  s += __shfl_xor(s, 2);
            s += __shfl_xor(s, 4);  s += __shfl_xor(s, 8);
            if (li == 0) ssqB[(mi * 16 + lg * 4 + r) * 4 + w] = s;
        }
    }
    __syncthreads();

    if (mat < 2) {
        // row-major staging [64][136]: col 0 = time, cols 1..127 = space
        #pragma unroll
        for (int mi = 0; mi < 4; mi++)
            #pragma unroll
            for (int ni = 0; ni < 2; ni++) {
                int e = w * 32 + ni * 16 + li;
                if (e < 127) {
                    #pragma unroll
                    for (int r = 0; r < 4; r++)
                        Ot[(mi * 16 + lg * 4 + r) * 136 + 1 + e] = f2bf(acc[mi][ni][r]);
                }
            }
        if (tid < 64) {
            float s = ssqB[tid * 4] + ssqB[tid * 4 + 1] + ssqB[tid * 4 + 2] + ssqB[tid * 4 + 3];
            float t = sqrtf(1.0f + s);
            Ot[tid * 136] = f2bf(mat == 0 ? -t : t);
        }
        __syncthreads();
        unsigned short* dst = ((mat == 0) ? Qs : Kb) + (h * 4096 + m0) * 128;
        #pragma unroll
        for (int p = 0; p < 4; p++) {
            int r = p * 16 + (tid >> 4), c = (tid & 15) * 8;
            *(short8_t*)(dst + r * 128 + c) = *(short8_t*)(Ot + r * 136 + c);
        }
    } else {
        // transposed staging [128][72]: row d = 1+e (space), row 0 = time
        #pragma unroll
        for (int mi = 0; mi < 4; mi++)
            #pragma unroll
            for (int ni = 0; ni < 2; ni++) {
                int e = w * 32 + ni * 16 + li;
                if (e < 127) {
                    uint2_t u;
                    u[0] = pk_bf16(acc[mi][ni][0], acc[mi][ni][1]);
                    u[1] = pk_bf16(acc[mi][ni][2], acc[mi][ni][3]);
                    *(uint2_t*)(OtT + (1 + e) * 72 + mi * 16 + lg * 4) = u;
                }
            }
        if (tid < 64) {
            float s = ssqB[tid * 4] + ssqB[tid * 4 + 1] + ssqB[tid * 4 + 2] + ssqB[tid * 4 + 3];
            OtT[tid] = f2bf(sqrtf(1.0f + s));
        }
        __syncthreads();
        int b = m0 >> 10, n0 = m0 & 1023;
        unsigned short* dst = Vt + (h * 4 + b) * 131072 + n0;
        #pragma unroll
        for (int p = 0; p < 4; p++) {
            int d = p * 32 + (tid >> 3), nc = (tid & 7) * 8;
            *(short8_t*)(dst + d * 1024 + nc) = *(short8_t*)(OtT + d * 72 + nc);
        }
    }
}

// ---------------------------------------------------------------------------
// Kernel 2: fused Lorentz attention — BARRIER-FREE main loop.
// grid = 1024 blocks (XCD-swizzled), 256 threads = 4 independent waves:
// (2 q-sets of 16 rows) x (2 KV-halves of 512). K/V fragments are loaded
// directly from global (L2-resident per XCD); only P round-trips through
// wave-private LDS (lgkmcnt fence, no barrier). Partials merged exactly at
// the end via one LDS exchange + single barrier.
// Score math: exp(-beta*arccosh(z)) = exp2(-beta*log2(z + sqrt(z^2-1)));
// gamma dropped (softmax shift-invariant); log2-domain softmax; defer-max.
// ---------------------------------------------------------------------------
__global__ __launch_bounds__(256, 3) void k_attn(
    const unsigned short* __restrict__ Qsg, const unsigned short* __restrict__ Kb,
    const unsigned short* __restrict__ Vt,
    const float* __restrict__ beta, const float* __restrict__ gamma,
    float* __restrict__ out, float* __restrict__ tsq)
{
    __shared__ __align__(16) unsigned char lds[42752];
    unsigned short* Ps  = (unsigned short*)lds;          // 4 x [16][72] bf16 = 9216
    float*          mrg = (float*)(lds + 9216);          // [2][16][130] f32 = 16640
    float*          ow  = (float*)(lds + 25856);         // [2][16][132] f32 = 16896

    const int tid = threadIdx.x, w = tid >> 6, lane = tid & 63;
    const int li = lane & 15, lg = lane >> 4;
    const int qsub = w >> 1, half = w & 1;

    // XCD-aware decode: all 32 blocks of one (h,b) land on one XCD
    const int bid = blockIdx.x;
    const int g = bid >> 3;
    const int hb = (bid & 7) + 8 * (g & 3);
    const int qs = g >> 2;                 // 0..31 (32-row q-set)
    const int h = hb >> 2, b = hb & 3;
    const int q0 = qs * 32;

    const unsigned short* Qp = Qsg + (h * 4096 + b * 1024) * 128;
    const unsigned short* Kp = Kb  + (h * 4096 + b * 1024) * 128;
    const unsigned short* Vp = Vt  + (h * 4 + b) * 131072;
    const float bet = beta[h];
    (void)gamma;

    // persistent Q fragments (16 q-rows per wave, B-operand layout)
    short8_t qf[4];
    const int qrow = q0 + qsub * 16 + li;
    #pragma unroll
    for (int kk = 0; kk < 4; kk++)
        qf[kk] = *(const short8_t*)(Qp + qrow * 128 + kk * 32 + lg * 8);

    float4_t amid[8];
    #pragma unroll
    for (int df = 0; df < 8; df++) amid[df] = (float4_t){0.f, 0.f, 0.f, 0.f};
    float m = -INFINITY, lsum = 0.0f;

    const int j0base = half * 512;
    for (int t = 0; t < 8; t++) {
        const int j0 = j0base + t * 64;

        // S^T = K . Qsgn — K A-fragments straight from global (L2)
        float4_t as[4];
        #pragma unroll
        for (int jf = 0; jf < 4; jf++) as[jf] = (float4_t){0.f, 0.f, 0.f, 0.f};
        #pragma unroll
        for (int jf = 0; jf < 4; jf++) {
            const unsigned short* kr0 = Kp + (j0 + jf * 16 + li) * 128 + lg * 8;
            short8_t k0 = *(const short8_t*)(kr0);
            short8_t k1 = *(const short8_t*)(kr0 + 32);
            short8_t k2 = *(const short8_t*)(kr0 + 64);
            short8_t k3 = *(const short8_t*)(kr0 + 96);
            as[jf] = MFMA(k0, qf[0], as[jf]);
            as[jf] = MFMA(k1, qf[1], as[jf]);
            as[jf] = MFMA(k2, qf[2], as[jf]);
            as[jf] = MFMA(k3, qf[3], as[jf]);
        }

        // scores in log2 domain: s2 = -beta * log2(z + sqrt(z^2-1))
        float s2[16];
        float tm = -INFINITY;
        #pragma unroll
        for (int jf = 0; jf < 4; jf++) {
            #pragma unroll
            for (int r = 0; r < 4; r++) {
                float z = fmaxf(-as[jf][r], 1.0f + 1e-6f);
                float wv = z + __builtin_amdgcn_sqrtf(__builtin_fmaf(z, z, -1.0f));
                float s = -bet * __builtin_amdgcn_logf(wv);
                s2[jf * 4 + r] = s;
                tm = fmaxf(tm, s);
            }
        }
        tm = fmaxf(tm, __shfl_xor(tm, 16));
        tm = fmaxf(tm, __shfl_xor(tm, 32));
        // defer-max: only rescale when the new tile max really exceeds m+8
        if (__any(tm > m + 8.0f)) {
            float mn = fmaxf(m, tm);
            float scale = __builtin_amdgcn_exp2f(m - mn);
            lsum *= scale;
            #pragma unroll
            for (int df = 0; df < 8; df++)
                #pragma unroll
                for (int r = 0; r < 4; r++) amid[df][r] *= scale;
            m = mn;
        }
        float ps_ = 0.0f;
        #pragma unroll
        for (int jf = 0; jf < 4; jf++) {
            float p0 = __builtin_amdgcn_exp2f(s2[jf * 4 + 0] - m);
            float p1 = __builtin_amdgcn_exp2f(s2[jf * 4 + 1] - m);
            float p2 = __builtin_amdgcn_exp2f(s2[jf * 4 + 2] - m);
            float p3 = __builtin_amdgcn_exp2f(s2[jf * 4 + 3] - m);
            ps_ += (p0 + p1) + (p2 + p3);
            uint2_t u; u[0] = pk_bf16(p0, p1); u[1] = pk_bf16(p2, p3);
            *(uint2_t*)(Ps + (w * 16 + li) * 72 + jf * 16 + lg * 4) = u;
        }
        ps_ += __shfl_xor(ps_, 16);
        ps_ += __shfl_xor(ps_, 32);
        lsum += ps_;
        // P writes are wave-local: drain LDS, fence the scheduler
        asm volatile("s_waitcnt lgkmcnt(0)" ::: "memory");
        __builtin_amdgcn_sched_barrier(0);

        // PV: mid^T[d,i] += V^T[d,j] * P^T[j,i] — V A-fragments from global
        #pragma unroll
        for (int kk2 = 0; kk2 < 2; kk2++) {
            short8_t Bp = *(short8_t*)(Ps + (w * 16 + li) * 72 + kk2 * 32 + lg * 8);
            const unsigned short* vr0 = Vp + li * 1024 + j0 + kk2 * 32 + lg * 8;
            #pragma unroll
            for (int df = 0; df < 8; df++) {
                short8_t A = *(const short8_t*)(vr0 + df * 16384);
                amid[df] = MFMA(A, Bp, amid[df]);
            }
        }
    }

    // ---- exact cross-half merge: half 1 dumps (amid, m, l); half 0 merges
    if (half == 1) {
        float* mb = mrg + qsub * 2080;     // 16*130
        #pragma unroll
        for (int df = 0; df < 8; df++)
            #pragma unroll
            for (int r = 0; r < 4; r++)
                mb[li * 130 + df * 16 + lg * 4 + r] = amid[df][r];
        if (lg == 0) { mb[li * 130 + 128] = m; mb[li * 130 + 129] = lsum; }
    }
    __syncthreads();
    if (half == 1) return;

    {
        float* mb = mrg + qsub * 2080;
        float mB = mb[li * 130 + 128];
        float lB = mb[li * 130 + 129];
        float mN = fmaxf(m, mB);
        float sA = __builtin_amdgcn_exp2f(m - mN);
        float sB = __builtin_amdgcn_exp2f(mB - mN);
        lsum = lsum * sA + lB * sB;
        #pragma unroll
        for (int df = 0; df < 8; df++)
            #pragma unroll
            for (int r = 0; r < 4; r++)
                amid[df][r] = amid[df][r] * sA + mb[li * 130 + df * 16 + lg * 4 + r] * sB;
    }
    asm volatile("s_waitcnt lgkmcnt(0)" ::: "memory");
    __builtin_amdgcn_sched_barrier(0);

    // epilogue: normalize softmax, Lorentz-midpoint rescale
    float invl = 1.0f / lsum;
    float ssq = 0.0f;
    #pragma unroll
    for (int df = 0; df < 8; df++) {
        #pragma unroll
        for (int r = 0; r < 4; r++) {
            float v = amid[df][r] * invl;
            amid[df][r] = v;
            ssq += v * v;
        }
    }
    ssq += __shfl_xor(ssq, 16);
    ssq += __shfl_xor(ssq, 32);
    float tmid = __shfl(amid[0][0], li);           // mid[d=0] for this lane's i
    float denom = fmaxf(2.0f * tmid * tmid - ssq, 1e-6f);  // -<m,m>_L
    float rs = 1.0f / sqrtf(denom);

    #pragma unroll
    for (int df = 0; df < 8; df++) {
        #pragma unroll
        for (int r = 0; r < 4; r++)
            ow[qsub * 2112 + li * 132 + df * 16 + lg * 4 + r] = amid[df][r] * rs;
    }
    asm volatile("s_waitcnt lgkmcnt(0)" ::: "memory");
    __builtin_amdgcn_sched_barrier(0);

    #pragma unroll
    for (int i = 0; i < 16; i++) {
        int n = q0 + qsub * 16 + i;
        float v0 = ow[qsub * 2112 + i * 132 + lane];
        float v1 = ow[qsub * 2112 + i * 132 + 64 + lane];
        float* orow = out + (b * 1024 + n) * 1017;
        if (lane == 0) tsq[h * 4096 + b * 1024 + n] = v0 * v0;
        else           orow[h * 127 + lane] = v0;        // comp = 1 + h*127 + (d-1)
        orow[h * 127 + 64 + lane] = v1;
    }
}

// ---------------------------------------------------------------------------
// Kernel 3: output time coordinate from per-head t^2
// ---------------------------------------------------------------------------
__global__ __launch_bounds__(256) void k_time(const float* __restrict__ tsq,
                                              float* __restrict__ out)
{
    int mrow = blockIdx.x * 256 + threadIdx.x;
    float s = 0.0f;
    #pragma unroll
    for (int h = 0; h < 8; h++) s += tsq[h * 4096 + mrow];
    out[mrow * 1017] = sqrtf(fmaxf(s - 7.0f, 1e-6f));
}

extern "C" void kernel_launch(void* const* d_in, const int* in_sizes, int n_in,
                              void* d_out, int out_size, void* d_ws, size_t ws_size,
                              hipStream_t stream)
{
    const float* x    = (const float*)d_in[0];
    const float* Wq   = (const float*)d_in[1];
    const float* bq   = (const float*)d_in[2];
    const float* Wk   = (const float*)d_in[3];
    const float* bk   = (const float*)d_in[4];
    const float* Wv   = (const float*)d_in[5];
    const float* bv   = (const float*)d_in[6];
    const float* beta = (const float*)d_in[7];
    const float* gam  = (const float*)d_in[8];
    float* out = (float*)d_out;

    unsigned char* ws = (unsigned char*)d_ws;
    unsigned short* Qs = (unsigned short*)(ws);              //  8 MB
    unsigned short* Kb = (unsigned short*)(ws + 8388608);    //  8 MB
    unsigned short* Vt = (unsigned short*)(ws + 16777216);   //  8 MB
    float*          ts = (float*)(ws + 25165824);            // 128 KB

    k_proj<<<dim3(64, 8, 3), 256, 0, stream>>>(x, Wq, bq, Wk, bk, Wv, bv, Qs, Kb, Vt);
    k_attn<<<dim3(1024), 256, 0, stream>>>(Qs, Kb, Vt, beta, gam, out, ts);
    k_time<<<dim3(16), 256, 0, stream>>>(ts, out);
}

// Round 5
// 136.684 us; speedup vs baseline: 1.6023x; 1.6023x over previous
//
#include <hip/hip_runtime.h>

typedef __attribute__((ext_vector_type(8))) short short8_t;
typedef __attribute__((ext_vector_type(4))) short short4_t;
typedef __attribute__((ext_vector_type(4))) float float4_t;
typedef __attribute__((ext_vector_type(2))) unsigned int uint2_t;

__device__ __forceinline__ unsigned short f2bf(float f) {
    unsigned u = __builtin_bit_cast(unsigned, f);
    u += 0x7FFFu + ((u >> 16) & 1u);
    return (unsigned short)(u >> 16);
}

// two f32 -> packed 2x bf16 (RNE) in one instruction
__device__ __forceinline__ unsigned pk_bf16(float a, float b) {
    unsigned r;
    asm("v_cvt_pk_bf16_f32 %0, %1, %2" : "=v"(r) : "v"(a), "v"(b));
    return r;
}

#define MFMA(A, B, C) __builtin_amdgcn_mfma_f32_16x16x32_bf16((A), (B), (C), 0, 0, 0)

// ---------------------------------------------------------------------------
// Kernel 1: per-head Lorentz FC projections (round-2 measured structure).
// grid = (64 row-tiles of 64, 8 heads, 3 mats). block = 256.
// mat 0 -> Qsgn [H][4096][128] bf16, comp0 = -t_q (Minkowski sign folded in)
// mat 1 -> K    [H][4096][128] bf16, comp0 = +t_k
// mat 2 -> Vt   [H][B=4][128][1024] bf16 (transposed: d-major), row 0 is t_v
// ---------------------------------------------------------------------------
__global__ __launch_bounds__(256) void k_proj(
    const float* __restrict__ x,
    const float* __restrict__ Wq, const float* __restrict__ bq,
    const float* __restrict__ Wk, const float* __restrict__ bk,
    const float* __restrict__ Wv, const float* __restrict__ bv,
    unsigned short* __restrict__ Qs, unsigned short* __restrict__ Kb,
    unsigned short* __restrict__ Vt)
{
    __shared__ __align__(16) unsigned char lds[17408 + 34816 + 1024];
    unsigned short* Xs  = (unsigned short*)lds;                    // [64][136] bf16
    unsigned short* Ws  = (unsigned short*)(lds + 17408);          // [128][136] bf16
    float*          ssqB = (float*)(lds + 17408 + 34816);          // [64][4]
    unsigned short* Ot  = Ws;                                      // reuse after MFMA
    unsigned short* OtT = Ws;                                      // mat=2: [128][72]

    const int tid = threadIdx.x;
    const int m0  = blockIdx.x * 64;
    const int h   = blockIdx.y;
    const int mat = blockIdx.z;
    const float* W  = (mat == 0) ? Wq : ((mat == 1) ? Wk : Wv);
    const float* bb = (mat == 0) ? bq : ((mat == 1) ? bk : bv);

    // stage X tile (64 x 128, fp32 -> bf16)
    #pragma unroll
    for (int p = 0; p < 8; p++) {
        int r = p * 8 + (tid >> 5), c = (tid & 31) * 4;
        float4_t v = *(const float4_t*)(x + (m0 + r) * 128 + c);
        uint2_t u; u[0] = pk_bf16(v[0], v[1]); u[1] = pk_bf16(v[2], v[3]);
        *(uint2_t*)(Xs + r * 136 + c) = u;
    }
    // stage W (127 x 128, zero row 127)
    #pragma unroll
    for (int p = 0; p < 16; p++) {
        int e = p * 8 + (tid >> 5), c = (tid & 31) * 4;
        float4_t v = {0.f, 0.f, 0.f, 0.f};
        if (e < 127) v = *(const float4_t*)(W + (h * 127 + e) * 128 + c);
        uint2_t u; u[0] = pk_bf16(v[0], v[1]); u[1] = pk_bf16(v[2], v[3]);
        *(uint2_t*)(Ws + e * 136 + c) = u;
    }
    __syncthreads();

    const int w = tid >> 6, lane = tid & 63, li = lane & 15, lg = lane >> 4;
    float4_t acc[4][2];
    #pragma unroll
    for (int i = 0; i < 4; i++)
        #pragma unroll
        for (int j = 0; j < 2; j++) acc[i][j] = (float4_t){0.f, 0.f, 0.f, 0.f};

    #pragma unroll
    for (int kk = 0; kk < 4; kk++) {
        short8_t Bf[2];
        #pragma unroll
        for (int ni = 0; ni < 2; ni++)
            Bf[ni] = *(short8_t*)(Ws + (w * 32 + ni * 16 + li) * 136 + kk * 32 + lg * 8);
        #pragma unroll
        for (int mi = 0; mi < 4; mi++) {
            short8_t A = *(short8_t*)(Xs + (mi * 16 + li) * 136 + kk * 32 + lg * 8);
            #pragma unroll
            for (int ni = 0; ni < 2; ni++) acc[mi][ni] = MFMA(A, Bf[ni], acc[mi][ni]);
        }
    }
    // bias
    #pragma unroll
    for (int ni = 0; ni < 2; ni++) {
        int e = w * 32 + ni * 16 + li;
        float bvv = (e < 127) ? bb[h * 127 + e] : 0.0f;
        #pragma unroll
        for (int mi = 0; mi < 4; mi++)
            #pragma unroll
            for (int r = 0; r < 4; r++) acc[mi][ni][r] += bvv;
    }
    // per-row sum of squares of space components (this wave's 32 cols)
    #pragma unroll
    for (int mi = 0; mi < 4; mi++) {
        #pragma unroll
        for (int r = 0; r < 4; r++) {
            float s = acc[mi][0][r] * acc[mi][0][r] + acc[mi][1][r] * acc[mi][1][r];
            s += __shfl_xor(s, 1);  s += __shfl_xor(s, 2);
            s += __shfl_xor(s, 4);  s += __shfl_xor(s, 8);
            if (li == 0) ssqB[(mi * 16 + lg * 4 + r) * 4 + w] = s;
        }
    }
    __syncthreads();

    if (mat < 2) {
        // row-major staging [64][136]: col 0 = time, cols 1..127 = space
        #pragma unroll
        for (int mi = 0; mi < 4; mi++)
            #pragma unroll
            for (int ni = 0; ni < 2; ni++) {
                int e = w * 32 + ni * 16 + li;
                if (e < 127) {
                    #pragma unroll
                    for (int r = 0; r < 4; r++)
                        Ot[(mi * 16 + lg * 4 + r) * 136 + 1 + e] = f2bf(acc[mi][ni][r]);
                }
            }
        if (tid < 64) {
            float s = ssqB[tid * 4] + ssqB[tid * 4 + 1] + ssqB[tid * 4 + 2] + ssqB[tid * 4 + 3];
            float t = sqrtf(1.0f + s);
            Ot[tid * 136] = f2bf(mat == 0 ? -t : t);
        }
        __syncthreads();
        unsigned short* dst = ((mat == 0) ? Qs : Kb) + (h * 4096 + m0) * 128;
        #pragma unroll
        for (int p = 0; p < 4; p++) {
            int r = p * 16 + (tid >> 4), c = (tid & 15) * 8;
            *(short8_t*)(dst + r * 128 + c) = *(short8_t*)(Ot + r * 136 + c);
        }
    } else {
        // transposed staging [128][72]: row d = 1+e (space), row 0 = time
        #pragma unroll
        for (int mi = 0; mi < 4; mi++)
            #pragma unroll
            for (int ni = 0; ni < 2; ni++) {
                int e = w * 32 + ni * 16 + li;
                if (e < 127) {
                    uint2_t u;
                    u[0] = pk_bf16(acc[mi][ni][0], acc[mi][ni][1]);
                    u[1] = pk_bf16(acc[mi][ni][2], acc[mi][ni][3]);
                    *(uint2_t*)(OtT + (1 + e) * 72 + mi * 16 + lg * 4) = u;
                }
            }
        if (tid < 64) {
            float s = ssqB[tid * 4] + ssqB[tid * 4 + 1] + ssqB[tid * 4 + 2] + ssqB[tid * 4 + 3];
            OtT[tid] = f2bf(sqrtf(1.0f + s));
        }
        __syncthreads();
        int b = m0 >> 10, n0 = m0 & 1023;
        unsigned short* dst = Vt + (h * 4 + b) * 131072 + n0;
        #pragma unroll
        for (int p = 0; p < 4; p++) {
            int d = p * 32 + (tid >> 3), nc = (tid & 7) * 8;
            *(short8_t*)(dst + d * 1024 + nc) = *(short8_t*)(OtT + d * 72 + nc);
        }
    }
}

// ---------------------------------------------------------------------------
// Kernel 2: fused Lorentz attention per (h,b), flash-style.
// 512 blocks (XCD-swizzled, 2 blocks/CU), 256 threads (4 waves), wave owns
// 16 q-rows. Round-3 pipeline: double-buffered K/V LDS; tile t+1's global
// loads issued into regs at top of tile t; ds_write after PV; ONE barrier
// per tile; setprio around MFMA clusters.
// Score math: beta==1 fast path (bench case): exp(-arccosh(z)) =
// 1/(z+sqrt(z^2-1)) -> P in (0,1] a-priori bounded -> NO online max, no
// rescales, no max reductions. Generic beta falls back to log2-domain
// online softmax with defer-max. gamma dropped (softmax shift-invariant).
// ---------------------------------------------------------------------------
__global__ __launch_bounds__(256, 2) void k_attn(
    const unsigned short* __restrict__ Qsg, const unsigned short* __restrict__ Kb,
    const unsigned short* __restrict__ Vt,
    const float* __restrict__ beta, const float* __restrict__ gamma,
    float* __restrict__ out, float* __restrict__ tsq)
{
    __shared__ __align__(16) unsigned char lds[80896];
    unsigned short* Kbuf0 = (unsigned short*)lds;             // [64][136]
    unsigned short* Kbuf1 = (unsigned short*)(lds + 17408);   // [64][136]
    unsigned short* Vbuf0 = (unsigned short*)(lds + 34816);   // [128][72]
    unsigned short* Vbuf1 = (unsigned short*)(lds + 53248);   // [128][72]
    unsigned short* Ps    = (unsigned short*)(lds + 71680);   // 4 x [16][72]
    float*          ow    = (float*)lds;                      // epilogue: 4 x [16][132] f32

    const int tid = threadIdx.x, w = tid >> 6, lane = tid & 63;
    const int li = lane & 15, lg = lane >> 4;

    // XCD-aware decode: all 16 q-tiles of one (h,b) land on one XCD
    const int bid = blockIdx.x;
    const int hb = (bid & 7) * 4 + (bid >> 7);
    const int qt = (bid >> 3) & 15;
    const int h = hb >> 2, b = hb & 3;
    const int q0 = qt * 64;

    const unsigned short* Qp = Qsg + (h * 4096 + b * 1024) * 128;
    const unsigned short* Kp = Kb  + (h * 4096 + b * 1024) * 128;
    const unsigned short* Vp = Vt  + (h * 4 + b) * 131072;
    const float bet = beta[h];
    const bool beta1 = (bet == 1.0f);
    (void)gamma;

    // per-thread staging indices
    const int kr = tid >> 4, kc = (tid & 15) * 8;   // K: rows p*16+kr, col kc
    const int vd = tid >> 3, vc = (tid & 7) * 8;    // V: rows p*32+vd, col vc
    const unsigned short* Kld = Kp + kr * 128 + kc;
    const unsigned short* Vld = Vp + vd * 1024 + vc;

    // persistent Q fragments (16 q-rows per wave, B-operand layout)
    short8_t qf[4];
    const int qrow = q0 + w * 16 + li;
    #pragma unroll
    for (int kk = 0; kk < 4; kk++)
        qf[kk] = *(const short8_t*)(Qp + qrow * 128 + kk * 32 + lg * 8);

    float4_t amid[8];
    #pragma unroll
    for (int df = 0; df < 8; df++) amid[df] = (float4_t){0.f, 0.f, 0.f, 0.f};
    float m = -INFINITY, lsum = 0.0f;

    short8_t kreg[4], vreg[4];
    // prologue: stage tile 0
    #pragma unroll
    for (int p = 0; p < 4; p++) {
        kreg[p] = *(const short8_t*)(Kld + p * 2048);
        vreg[p] = *(const short8_t*)(Vld + p * 32768);
    }
    #pragma unroll
    for (int p = 0; p < 4; p++) {
        *(short8_t*)(Kbuf0 + (p * 16 + kr) * 136 + kc) = kreg[p];
        *(short8_t*)(Vbuf0 + (p * 32 + vd) * 72 + vc) = vreg[p];
    }
    __syncthreads();

    for (int t = 0; t < 16; t++) {
        unsigned short* Kc = (t & 1) ? Kbuf1 : Kbuf0;
        unsigned short* Vc = (t & 1) ? Vbuf1 : Vbuf0;
        unsigned short* Kn = (t & 1) ? Kbuf0 : Kbuf1;
        unsigned short* Vn = (t & 1) ? Vbuf0 : Vbuf1;

        // issue next tile's global loads NOW — land during this tile's compute
        if (t < 15) {
            const int j0n = (t + 1) * 64;
            #pragma unroll
            for (int p = 0; p < 4; p++) {
                kreg[p] = *(const short8_t*)(Kld + j0n * 128 + p * 2048);
                vreg[p] = *(const short8_t*)(Vld + p * 32768 + j0n);
            }
        }
        __builtin_amdgcn_sched_barrier(0);   // keep loads issued up here

        // S^T = K . Qsgn  (inner products, sign pre-folded into Qsgn)
        float4_t as[4];
        #pragma unroll
        for (int jf = 0; jf < 4; jf++) as[jf] = (float4_t){0.f, 0.f, 0.f, 0.f};
        __builtin_amdgcn_s_setprio(1);
        #pragma unroll
        for (int kk = 0; kk < 4; kk++) {
            #pragma unroll
            for (int jf = 0; jf < 4; jf++) {
                short8_t A = *(short8_t*)(Kc + (jf * 16 + li) * 136 + kk * 32 + lg * 8);
                as[jf] = MFMA(A, qf[kk], as[jf]);
            }
        }
        __builtin_amdgcn_s_setprio(0);

        float ps_ = 0.0f;
        if (beta1) {
            // beta==1: P = 1/(z+sqrt(z^2-1)) in (0,1] — bounded, no max needed
            #pragma unroll
            for (int jf = 0; jf < 4; jf++) {
                float p[4];
                #pragma unroll
                for (int r = 0; r < 4; r++) {
                    float z = fmaxf(-as[jf][r], 1.0f + 1e-6f);
                    float wv = z + __builtin_amdgcn_sqrtf(__builtin_fmaf(z, z, -1.0f));
                    p[r] = __builtin_amdgcn_rcpf(wv);
                    ps_ += p[r];
                }
                uint2_t u; u[0] = pk_bf16(p[0], p[1]); u[1] = pk_bf16(p[2], p[3]);
                *(uint2_t*)(Ps + (w * 16 + li) * 72 + jf * 16 + lg * 4) = u;
            }
        } else {
            // generic beta: log2-domain online softmax with defer-max
            float s2[16];
            float tm = -INFINITY;
            #pragma unroll
            for (int jf = 0; jf < 4; jf++) {
                #pragma unroll
                for (int r = 0; r < 4; r++) {
                    float z = fmaxf(-as[jf][r], 1.0f + 1e-6f);
                    float wv = z + __builtin_amdgcn_sqrtf(__builtin_fmaf(z, z, -1.0f));
                    float s = -bet * __builtin_amdgcn_logf(wv);
                    s2[jf * 4 + r] = s;
                    tm = fmaxf(tm, s);
                }
            }
            tm = fmaxf(tm, __shfl_xor(tm, 16));
            tm = fmaxf(tm, __shfl_xor(tm, 32));
            if (__any(tm > m + 8.0f)) {
                float mn = fmaxf(m, tm);
                float scale = __builtin_amdgcn_exp2f(m - mn);
                lsum *= scale;
                #pragma unroll
                for (int df = 0; df < 8; df++)
                    #pragma unroll
                    for (int r = 0; r < 4; r++) amid[df][r] *= scale;
                m = mn;
            }
            #pragma unroll
            for (int jf = 0; jf < 4; jf++) {
                float p0 = __builtin_amdgcn_exp2f(s2[jf * 4 + 0] - m);
                float p1 = __builtin_amdgcn_exp2f(s2[jf * 4 + 1] - m);
                float p2 = __builtin_amdgcn_exp2f(s2[jf * 4 + 2] - m);
                float p3 = __builtin_amdgcn_exp2f(s2[jf * 4 + 3] - m);
                ps_ += (p0 + p1) + (p2 + p3);
                uint2_t u; u[0] = pk_bf16(p0, p1); u[1] = pk_bf16(p2, p3);
                *(uint2_t*)(Ps + (w * 16 + li) * 72 + jf * 16 + lg * 4) = u;
            }
        }
        ps_ += __shfl_xor(ps_, 16);
        ps_ += __shfl_xor(ps_, 32);
        lsum += ps_;
        // P writes are wave-local: drain LDS, fence the scheduler
        asm volatile("s_waitcnt lgkmcnt(0)" ::: "memory");
        __builtin_amdgcn_sched_barrier(0);

        // PV: mid^T[d,i] += V^T[d,j] * P^T[j,i]
        __builtin_amdgcn_s_setprio(1);
        #pragma unroll
        for (int kk2 = 0; kk2 < 2; kk2++) {
            short8_t Bp = *(short8_t*)(Ps + (w * 16 + li) * 72 + kk2 * 32 + lg * 8);
            #pragma unroll
            for (int df = 0; df < 8; df++) {
                short8_t A = *(short8_t*)(Vc + (df * 16 + li) * 72 + kk2 * 32 + lg * 8);
                amid[df] = MFMA(A, Bp, amid[df]);
            }
        }
        __builtin_amdgcn_s_setprio(0);

        // write next tile into the alternate buffer (loads have landed by now)
        if (t < 15) {
            #pragma unroll
            for (int p = 0; p < 4; p++) {
                *(short8_t*)(Kn + (p * 16 + kr) * 136 + kc) = kreg[p];
                *(short8_t*)(Vn + (p * 32 + vd) * 72 + vc) = vreg[p];
            }
        }
        __syncthreads();   // single barrier per tile
    }

    // epilogue: normalize softmax, Lorentz-midpoint rescale
    float invl = 1.0f / lsum;
    float ssq = 0.0f;
    #pragma unroll
    for (int df = 0; df < 8; df++) {
        #pragma unroll
        for (int r = 0; r < 4; r++) {
            float v = amid[df][r] * invl;
            amid[df][r] = v;
            ssq += v * v;
        }
    }
    ssq += __shfl_xor(ssq, 16);
    ssq += __shfl_xor(ssq, 32);
    float tmid = __shfl(amid[0][0], li);           // mid[d=0] for this lane's i
    float denom = fmaxf(2.0f * tmid * tmid - ssq, 1e-6f);  // -<m,m>_L
    float rs = 1.0f / sqrtf(denom);

    // final barrier of the loop already passed; all waves done with LDS
    #pragma unroll
    for (int df = 0; df < 8; df++) {
        #pragma unroll
        for (int r = 0; r < 4; r++)
            ow[w * 2112 + li * 132 + df * 16 + lg * 4 + r] = amid[df][r] * rs;
    }
    asm volatile("s_waitcnt lgkmcnt(0)" ::: "memory");
    __builtin_amdgcn_sched_barrier(0);

    #pragma unroll
    for (int i = 0; i < 16; i++) {
        int n = q0 + w * 16 + i;
        float v0 = ow[w * 2112 + i * 132 + lane];
        float v1 = ow[w * 2112 + i * 132 + 64 + lane];
        float* orow = out + (b * 1024 + n) * 1017;
        if (lane == 0) tsq[h * 4096 + b * 1024 + n] = v0 * v0;
        else           orow[h * 127 + lane] = v0;        // comp = 1 + h*127 + (d-1)
        orow[h * 127 + 64 + lane] = v1;
    }
}

// ---------------------------------------------------------------------------
// Kernel 3: output time coordinate from per-head t^2
// ---------------------------------------------------------------------------
__global__ __launch_bounds__(256) void k_time(const float* __restrict__ tsq,
                                              float* __restrict__ out)
{
    int mrow = blockIdx.x * 256 + threadIdx.x;
    float s = 0.0f;
    #pragma unroll
    for (int h = 0; h < 8; h++) s += tsq[h * 4096 + mrow];
    out[mrow * 1017] = sqrtf(fmaxf(s - 7.0f, 1e-6f));
}

extern "C" void kernel_launch(void* const* d_in, const int* in_sizes, int n_in,
                              void* d_out, int out_size, void* d_ws, size_t ws_size,
                              hipStream_t stream)
{
    const float* x    = (const float*)d_in[0];
    const float* Wq   = (const float*)d_in[1];
    const float* bq   = (const float*)d_in[2];
    const float* Wk   = (const float*)d_in[3];
    const float* bk   = (const float*)d_in[4];
    const float* Wv   = (const float*)d_in[5];
    const float* bv   = (const float*)d_in[6];
    const float* beta = (const float*)d_in[7];
    const float* gam  = (const float*)d_in[8];
    float* out = (float*)d_out;

    unsigned char* ws = (unsigned char*)d_ws;
    unsigned short* Qs = (unsigned short*)(ws);              //  8 MB
    unsigned short* Kb = (unsigned short*)(ws + 8388608);    //  8 MB
    unsigned short* Vt = (unsigned short*)(ws + 16777216);   //  8 MB
    float*          ts = (float*)(ws + 25165824);            // 128 KB

    k_proj<<<dim3(64, 8, 3), 256, 0, stream>>>(x, Wq, bq, Wk, bk, Wv, bv, Qs, Kb, Vt);
    k_attn<<<dim3(512), 256, 0, stream>>>(Qs, Kb, Vt, beta, gam, out, ts);
    k_time<<<dim3(16), 256, 0, stream>>>(ts, out);
}